// Round 2
// baseline (630.616 us; speedup 1.0000x reference)
//
#include <hip/hip_runtime.h>

// 2-layer LSTM (H=12), B=8192, T=1024 + 64 free-running steps.
// R8: register-closed recurrence (R7) + STAGE-WISE ILP.
// R7 post-mortem: 564 us, VALUBusy 36.5% -> ~640 cy/step of dependency stalls.
// The 3 unit-chunks' act chains (each ~90 cy of serial exp->rcp->exp->rcp
// trans latency) were emitted sequentially. R8 restructures act as act3():
// every pipeline stage is issued for all 3 chunks back-to-back, so each
// chunk's trans latency hides under the other two chunks' issue.
// Also: packed f16 B fragment (Bv) is loop-carried, so each step opens with
// 3 immediately-issuable MFMAs and only 3 f16 cvts per cell are new.
//
// Layout (unchanged from R7, harness-verified):
//   Row order R = 4*v + q; chunk c row (lane&15) -> v=4c+(m>>2), q=m&3.
//   K order k = 8*(u%4) + (u/4); B slot (g,j<3) = h_{4j+g} -> lane-local
//   D->B handoff; pads at j=3,7. Cell1 A zeros on h2 slots.
// Fragment maps (gfx950, HW-verified):
//   A[m=lane&15][k=8*(lane>>4)+j], B[k=8*(lane>>4)+j][n=lane&15],
//   D[row=4*(lane>>4)+reg][col=lane&15].

typedef _Float16 v8h  __attribute__((ext_vector_type(8)));
typedef float    v4f  __attribute__((ext_vector_type(4)));

constexpr int T   = 1024;
constexpr int FUT = 64;
constexpr int TT  = T + FUT;   // 1088
constexpr int B   = 8192;

static __device__ __forceinline__ float fexp2(float x){ return __builtin_amdgcn_exp2f(x); }
static __device__ __forceinline__ float frcp (float x){ return __builtin_amdgcn_rcpf(x); }

__global__ __launch_bounds__(64) void lstm_reg_kernel(
    const float* __restrict__ input,
    const float* __restrict__ w_ih1, const float* __restrict__ w_hh1,
    const float* __restrict__ b_ih1, const float* __restrict__ b_hh1,
    const float* __restrict__ w_ih2, const float* __restrict__ w_hh2,
    const float* __restrict__ b_ih2, const float* __restrict__ b_hh2,
    const float* __restrict__ w_lin, const float* __restrict__ b_lin,
    float* __restrict__ out)
{
  const int lane = threadIdx.x & 63;
  const int g    = lane >> 4;       // lane group: unit residue (u mod 4)
  const int n    = lane & 15;       // element column
  const int e0   = blockIdx.x * 16;

  const float L2E = 1.4426950408889634f;
  const float sc[4] = { -L2E, -L2E, 2.0f * L2E, -L2E };  // i,f,g,o prescale
  const float TWO_L2E = 2.885390081777927f;

  // ---------------- A fragments: 3 chunks per cell, prescaled ------------
  v8h A1[3], A2[3];
  {
    const int q = n & 3;
    #pragma unroll
    for (int c = 0; c < 3; ++c) {
      const int v   = 4 * c + (n >> 2);
      const int row = q * 12 + v;
      v8h a1 = {0,0,0,0,0,0,0,0}, a2 = {0,0,0,0,0,0,0,0};
      #pragma unroll
      for (int j = 0; j < 3; ++j) {
        const int u = 4 * j + g;
        a1[j]     = (_Float16)(sc[q] * w_hh1[row * 12 + u]);   // cell1: h1 cols
        a2[j]     = (_Float16)(sc[q] * w_ih2[row * 12 + u]);   // cell2: h1 cols
        a2[j + 4] = (_Float16)(sc[q] * w_hh2[row * 12 + u]);   // cell2: h2 cols
      }
      A1[c] = a1; A2[c] = a2;
    }
  }

  // ---------------- C bias fragments + x weights + y weights -------------
  v4f  C1[3], C2[3];
  float wi1[3][4], wl[3];
  #pragma unroll
  for (int c = 0; c < 3; ++c) {
    const int v = 4 * c + g;
    #pragma unroll
    for (int r = 0; r < 4; ++r) {
      C1[c][r]  = sc[r] * (b_ih1[r * 12 + v] + b_hh1[r * 12 + v]);
      C2[c][r]  = sc[r] * (b_ih2[r * 12 + v] + b_hh2[r * 12 + v]);
      wi1[c][r] = sc[r] * w_ih1[r * 12 + v];
    }
    wl[c] = w_lin[v];
  }
  const float blin = b_lin[0];

  // ---------------- state (all registers) --------------------------------
  float c1s[3] = {0,0,0}, c2s[3] = {0,0,0};
  v8h Bv = {0,0,0,0,0,0,0,0};       // loop-carried packed {h1[0..2],0,h2[0..2],0}

  const float* xrow   = input + (size_t)(e0 + n) * T;
  float*       yrow   = out   + (size_t)(e0 + n) * TT;
  const bool   ystore = (g == 3);
  const float  xl     = xrow[T - 1];

  // Stage-wise triple act: all 3 chunks advance one stage at a time so the
  // serial trans latency of each chunk hides under the others' issue.
  auto act3 = [&](const float (&G)[3][4], float (&cs)[3], float (&h)[3]) {
    float Ai[3], Af[3], Eg[3], Ao[3];
    #pragma unroll
    for (int c = 0; c < 3; ++c) Ai[c] = fexp2(G[c][0]);
    #pragma unroll
    for (int c = 0; c < 3; ++c) Af[c] = fexp2(G[c][1]);
    #pragma unroll
    for (int c = 0; c < 3; ++c) Eg[c] = fexp2(G[c][2]);
    #pragma unroll
    for (int c = 0; c < 3; ++c) Ao[c] = fexp2(G[c][3]);
    float pf[3], P[3], R[3], Nn[3];
    #pragma unroll
    for (int c = 0; c < 3; ++c) { pf[c] = 1.0f + Af[c]; P[c] = (1.0f + Ai[c]) * (1.0f + Eg[c]); }
    #pragma unroll
    for (int c = 0; c < 3; ++c) R[c]  = frcp(P[c] * pf[c]);
    #pragma unroll
    for (int c = 0; c < 3; ++c) Nn[c] = fmaf(cs[c], P[c], (Eg[c] - 1.0f) * pf[c]);
    float Ec[3];
    #pragma unroll
    for (int c = 0; c < 3; ++c) { cs[c] = Nn[c] * R[c]; }
    #pragma unroll
    for (int c = 0; c < 3; ++c) Ec[c] = fexp2(TWO_L2E * cs[c]);
    float R2[3];
    #pragma unroll
    for (int c = 0; c < 3; ++c) R2[c] = frcp((1.0f + Ao[c]) * (1.0f + Ec[c]));
    #pragma unroll
    for (int c = 0; c < 3; ++c) h[c] = (Ec[c] - 1.0f) * R2[c];
  };

  auto step = [&](float x) -> float {
    // ---- cell 1: MFMAs issue first (Bv carried from previous step) ------
    v4f D0 = __builtin_amdgcn_mfma_f32_16x16x32_f16(A1[0], Bv, C1[0], 0, 0, 0);
    v4f D1 = __builtin_amdgcn_mfma_f32_16x16x32_f16(A1[1], Bv, C1[1], 0, 0, 0);
    v4f D2 = __builtin_amdgcn_mfma_f32_16x16x32_f16(A1[2], Bv, C1[2], 0, 0, 0);

    float G1[3][4];
    #pragma unroll
    for (int r = 0; r < 4; ++r) G1[0][r] = fmaf(wi1[0][r], x, D0[r]);
    #pragma unroll
    for (int r = 0; r < 4; ++r) G1[1][r] = fmaf(wi1[1][r], x, D1[r]);
    #pragma unroll
    for (int r = 0; r < 4; ++r) G1[2][r] = fmaf(wi1[2][r], x, D2[r]);

    float h1f[3];
    act3(G1, c1s, h1f);

    // ---- cell 2: overwrite h1 slots only; h2 slots unchanged ------------
    v8h B2 = Bv;
    B2[0] = (_Float16)h1f[0]; B2[1] = (_Float16)h1f[1]; B2[2] = (_Float16)h1f[2];

    v4f E0 = __builtin_amdgcn_mfma_f32_16x16x32_f16(A2[0], B2, C2[0], 0, 0, 0);
    v4f E1 = __builtin_amdgcn_mfma_f32_16x16x32_f16(A2[1], B2, C2[1], 0, 0, 0);
    v4f E2 = __builtin_amdgcn_mfma_f32_16x16x32_f16(A2[2], B2, C2[2], 0, 0, 0);

    float G2[3][4];
    #pragma unroll
    for (int r = 0; r < 4; ++r) G2[0][r] = E0[r];
    #pragma unroll
    for (int r = 0; r < 4; ++r) G2[1][r] = E1[r];
    #pragma unroll
    for (int r = 0; r < 4; ++r) G2[2][r] = E2[r];

    float h2f[3];
    act3(G2, c2s, h2f);

    // Carry packed B for next step's cell1 (reuse cell2's h1 pack).
    Bv = B2;
    Bv[4] = (_Float16)h2f[0]; Bv[5] = (_Float16)h2f[1]; Bv[6] = (_Float16)h2f[2];

    // ---- y(t) = w_lin . h2(t) + b: off the recurrence critical path -----
    float yp = h2f[0] * wl[0];
    yp = fmaf(h2f[1], wl[1], yp);
    yp = fmaf(h2f[2], wl[2], yp);
    yp += __shfl_xor(yp, 16);
    yp += __shfl_xor(yp, 32);
    return yp + blin;
  };

  // Software-pipelined x loads: next float4 issued before the 4 substeps.
  float4 xv = *reinterpret_cast<const float4*>(xrow);
  for (int tb = 0; tb < TT; tb += 4) {
    float4 xnext;
    if (tb + 4 < T) xnext = *reinterpret_cast<const float4*>(xrow + tb + 4);
    else            xnext = make_float4(xl, xl, xl, xl);

    float4 yb;
    yb.x = step(xv.x);
    yb.y = step(xv.y);
    yb.z = step(xv.z);
    yb.w = step(xv.w);
    if (ystore) *reinterpret_cast<float4*>(yrow + tb) = yb;
    xv = xnext;
  }
}

extern "C" void kernel_launch(void* const* d_in, const int* in_sizes, int n_in,
                              void* d_out, int out_size, void* d_ws, size_t ws_size,
                              hipStream_t stream) {
  const float* input = (const float*)d_in[0];
  const float* w_ih1 = (const float*)d_in[2];
  const float* w_hh1 = (const float*)d_in[3];
  const float* b_ih1 = (const float*)d_in[4];
  const float* b_hh1 = (const float*)d_in[5];
  const float* w_ih2 = (const float*)d_in[6];
  const float* w_hh2 = (const float*)d_in[7];
  const float* b_ih2 = (const float*)d_in[8];
  const float* b_hh2 = (const float*)d_in[9];
  const float* w_lin = (const float*)d_in[10];
  const float* b_lin = (const float*)d_in[11];
  float* out = (float*)d_out;

  dim3 grid(B / 16);   // 512 single-wave chains; 2 per CU
  dim3 block(64);
  hipLaunchKernelGGL(lstm_reg_kernel, grid, block, 0, stream,
                     input, w_ih1, w_hh1, b_ih1, b_hh1,
                     w_ih2, w_hh2, b_ih2, b_hh2, w_lin, b_lin, out);
}